// Round 5
// baseline (250.740 us; speedup 1.0000x reference)
//
#include <hip/hip_runtime.h>
#include <hip/hip_bf16.h>
#include <stdint.h>

typedef __attribute__((ext_vector_type(8))) short short8;
typedef __attribute__((ext_vector_type(4))) float floatx4;
typedef __attribute__((ext_vector_type(16))) float floatx16;

#define MFMA16(a, b, c) __builtin_amdgcn_mfma_f32_16x16x32_bf16(a, b, c, 0, 0, 0)
#define MFMA32(a, b, c) __builtin_amdgcn_mfma_f32_32x32x16_bf16(a, b, c, 0, 0, 0)

static __device__ __forceinline__ void gload_lds16(const __hip_bfloat16* g, __hip_bfloat16* l) {
  __builtin_amdgcn_global_load_lds(
      (const __attribute__((address_space(1))) void*)g,
      (__attribute__((address_space(3))) void*)l,
      16, 0, 0);
}

// ---------------- fp32 -> bf16 convert ----------------
__global__ void f2bf(const float* __restrict__ in, __hip_bfloat16* __restrict__ out, int n) {
  const int stride = gridDim.x * blockDim.x * 4;
  for (int i = (blockIdx.x * blockDim.x + threadIdx.x) * 4; i < n; i += stride) {
    const float4 v = *(const float4*)(in + i);
    __hip_bfloat16 t[4] = {__float2bfloat16(v.x), __float2bfloat16(v.y),
                           __float2bfloat16(v.z), __float2bfloat16(v.w)};
    *(short4*)(out + i) = *(const short4*)t;
  }
}

// ---------------- GEMM: C = A @ Bt^T  (A: MxK, Bt: NxK, both bf16 row-major) ----------------
template <typename OUT_T>
__global__ __launch_bounds__(256)
void gemm_bt(const __hip_bfloat16* __restrict__ A, const __hip_bfloat16* __restrict__ Bt,
             OUT_T* __restrict__ C, int M, int N, int K) {
  __shared__ __hip_bfloat16 As[2][128 * 32];
  __shared__ __hip_bfloat16 Bs[2][128 * 32];
  const int tid = threadIdx.x;
  const int wid = tid >> 6, lane = tid & 63;
  const int lg = lane >> 4, lr = lane & 15;
  const int wr = wid >> 1, wc = wid & 1;
  const int m0 = blockIdx.x * 128, n0 = blockIdx.y * 128;
  const int nk = K >> 5;

  floatx4 acc[4][4];
#pragma unroll
  for (int mi = 0; mi < 4; ++mi)
#pragma unroll
    for (int ni = 0; ni < 4; ++ni) acc[mi][ni] = (floatx4)(0.0f);

  auto stage = [&](int buf, int kt) {
    const int k0 = kt << 5;
#pragma unroll
    for (int i = 0; i < 2; ++i) {
      const int e = (i * 256 + tid) * 8;
      const int row = e >> 5, col = e & 31;
      gload_lds16(A + (size_t)(m0 + row) * K + k0 + col, &As[buf][e]);
    }
#pragma unroll
    for (int i = 0; i < 2; ++i) {
      const int e = (i * 256 + tid) * 8;
      const int row = e >> 5, col = e & 31;
      gload_lds16(Bt + (size_t)(n0 + row) * K + k0 + col, &Bs[buf][e]);
    }
  };

  stage(0, 0);
  __syncthreads();

  for (int kt = 0; kt < nk; ++kt) {
    const int cur = kt & 1;
    if (kt + 1 < nk) stage(cur ^ 1, kt + 1);
    short8 af[4], bfr[4];
#pragma unroll
    for (int mi = 0; mi < 4; ++mi)
      af[mi] = *(const short8*)&As[cur][(wr * 64 + mi * 16 + lr) * 32 + lg * 8];
#pragma unroll
    for (int ni = 0; ni < 4; ++ni)
      bfr[ni] = *(const short8*)&Bs[cur][(wc * 64 + ni * 16 + lr) * 32 + lg * 8];
#pragma unroll
    for (int mi = 0; mi < 4; ++mi)
#pragma unroll
      for (int ni = 0; ni < 4; ++ni) acc[mi][ni] = MFMA16(af[mi], bfr[ni], acc[mi][ni]);
    __syncthreads();
  }

#pragma unroll
  for (int mi = 0; mi < 4; ++mi)
#pragma unroll
    for (int ni = 0; ni < 4; ++ni) {
      const int row = m0 + wr * 64 + mi * 16 + lg * 4;
      const int col = n0 + wc * 64 + ni * 16 + lr;
#pragma unroll
      for (int r = 0; r < 4; ++r) {
        C[(size_t)(row + r) * N + col] = (OUT_T)acc[mi][ni][r];
      }
    }
}

// ---------------- RMSNorm + RoPE + scatter to (B,H,S,D) ----------------
__global__ __launch_bounds__(256)
void normrope(const __hip_bfloat16* __restrict__ qkv, const float* __restrict__ cosb,
              const float* __restrict__ sinb, const float* __restrict__ qw,
              const float* __restrict__ kw, __hip_bfloat16* __restrict__ Q,
              __hip_bfloat16* __restrict__ K, __hip_bfloat16* __restrict__ V) {
  const int m = blockIdx.x;            // b*2048 + s
  const int b = m >> 11, s = m & 2047;
  const int wid = threadIdx.x >> 6, lane = threadIdx.x & 63;
  const size_t qkvrow = (size_t)m * 3072;
  const float c1 = cosb[(size_t)m * 128 + lane], s1 = sinb[(size_t)m * 128 + lane];
  const float c2 = cosb[(size_t)m * 128 + lane + 64], s2 = sinb[(size_t)m * 128 + lane + 64];
  for (int h = wid * 6; h < wid * 6 + 6; ++h) {
    const float x1 = __bfloat162float(qkv[qkvrow + h * 128 + lane]);
    const float x2 = __bfloat162float(qkv[qkvrow + h * 128 + lane + 64]);
    if (h < 20) {
      float ss = x1 * x1 + x2 * x2;
      ss += __shfl_xor(ss, 1);  ss += __shfl_xor(ss, 2);  ss += __shfl_xor(ss, 4);
      ss += __shfl_xor(ss, 8);  ss += __shfl_xor(ss, 16); ss += __shfl_xor(ss, 32);
      const float rs = rsqrtf(ss * (1.0f / 128.0f) + 1e-6f);
      const float* w = (h < 16) ? qw : kw;
      const float n1 = x1 * rs * w[lane], n2 = x2 * rs * w[lane + 64];
      const float o1 = n1 * c1 - n2 * s1;
      const float o2 = n2 * c2 + n1 * s2;
      if (h < 16) {
        const size_t base = ((size_t)(b * 16 + h) * 2048 + s) * 128;
        Q[base + lane] = __float2bfloat16(o1);
        Q[base + lane + 64] = __float2bfloat16(o2);
      } else {
        const size_t base = ((size_t)(b * 4 + h - 16) * 2048 + s) * 128;
        K[base + lane] = __float2bfloat16(o1);
        K[base + lane + 64] = __float2bfloat16(o2);
      }
    } else {
      const size_t base = ((size_t)(b * 4 + h - 20) * 2048 + s) * 128;
      V[base + lane] = qkv[qkvrow + h * 128 + lane];
      V[base + lane + 64] = qkv[qkvrow + h * 128 + lane + 64];
    }
  }
}

// ---------------- V transpose: (BHkv,S,D) -> (BHkv,D,S) ----------------
__global__ __launch_bounds__(256)
void vtrans(const __hip_bfloat16* __restrict__ V, __hip_bfloat16* __restrict__ Vt) {
  __shared__ short L[64 * 65];  // [d_local][s_local], stride 65 kills bank conflicts
  const int tid = threadIdx.x;
  const int s0 = blockIdx.x * 64, d0 = blockIdx.y * 64, bz = blockIdx.z;
  const __hip_bfloat16* src = V + (size_t)bz * 2048 * 128;
#pragma unroll
  for (int i = 0; i < 2; ++i) {
    const int slot = i * 256 + tid;
    const int srow = slot >> 3, c8 = (slot & 7) * 8;
    short8 v = *(const short8*)(src + (size_t)(s0 + srow) * 128 + d0 + c8);
#pragma unroll
    for (int j = 0; j < 8; ++j) L[(c8 + j) * 65 + srow] = v[j];
  }
  __syncthreads();
  __hip_bfloat16* dst = Vt + (size_t)bz * 128 * 2048;
#pragma unroll
  for (int i = 0; i < 2; ++i) {
    const int slot = i * 256 + tid;
    const int drow = slot >> 3, sc8 = (slot & 7) * 8;
    short8 o;
#pragma unroll
    for (int j = 0; j < 8; ++j) o[j] = L[drow * 65 + sc8 + j];
    *(short8*)(dst + (size_t)(d0 + drow) * 2048 + s0 + sc8) = o;
  }
}

// ---------------- Flash attention (non-causal, GQA 4:1), 32x32 MFMA, S^T form ----------------
// Each wave: 32 q-rows, full in-register softmax (static max), P^T redistributed via
// cvt_pk_bf16 + shfl_xor(32); zero P LDS traffic. l via ones-MFMA. LDS-transposed epilogue.
__global__ __launch_bounds__(256, 2)
void fattn(const __hip_bfloat16* __restrict__ Qg, const __hip_bfloat16* __restrict__ Kg,
           const __hip_bfloat16* __restrict__ Vtg, __hip_bfloat16* __restrict__ Og) {
  __shared__ short SMEM[17920];      // Ksf [64][136] (8704) + Vtl [128][72] (9216)
  short* Ksf = SMEM;
  short* Vtl = SMEM + 8704;

  const int tid = threadIdx.x, wid = tid >> 6, lane = tid & 63;
  const int l31 = lane & 31, hi = lane >> 5;
  const int qt = blockIdx.x, bh = blockIdx.y;
  const int b = bh >> 4, h = bh & 15, hkv = h >> 2;
  const int q0w = qt * 128 + wid * 32;

  // Q as B-fragments for 32x32x16: B[col = l&31 -> q][k = hi*8 + j], k-step 16 over d
  const __hip_bfloat16* Qrow = Qg + ((size_t)((b * 16 + h) * 2048 + q0w + l31)) * 128;
  short8 qf2[8];
#pragma unroll
  for (int ks = 0; ks < 8; ++ks) qf2[ks] = *(const short8*)(Qrow + ks * 16 + hi * 8);

  const __hip_bfloat16* Kbase = Kg + (size_t)(b * 4 + hkv) * 2048 * 128;
  const __hip_bfloat16* Vtbase = Vtg + (size_t)(b * 4 + hkv) * 128 * 2048;

  int koff[4], kldsoff[4], voff[4], vldsoff[4];
#pragma unroll
  for (int i = 0; i < 4; ++i) {
    const int idx = i * 256 + tid;
    const int kkv = idx >> 4, kd = (idx & 15) * 8;
    koff[i] = kkv * 128 + kd;
    kldsoff[i] = kkv * 136 + kd;
    const int vd = idx >> 3, vc = (idx & 7) * 8;
    voff[i] = vd * 2048 + vc;
    vldsoff[i] = vd * 72 + vc;
  }

  // oacc[dblk]: O^T[d = dblk*32 + (reg&3)+8*(reg>>2)+4*hi][q = l31]
  floatx16 oacc[4];
#pragma unroll
  for (int dblk = 0; dblk < 4; ++dblk) oacc[dblk] = (floatx16)(0.0f);
  floatx16 lacc = (floatx16)(0.0f);

  short8 ones;
#pragma unroll
  for (int j = 0; j < 8; ++j) ones[j] = (short)0x3F80;  // bf16 1.0

  const float SC2 = 0.12753102497113446f;   // (1/sqrt(128)) * log2(e)
  const float OFF2 = 17.31234049066756f;    // 12 * log2(e)

  short8 kreg[4], vreg[4];
  auto loadKV = [&](int kt) {
    const __hip_bfloat16* kp = Kbase + (size_t)kt * 64 * 128;
    const __hip_bfloat16* vp = Vtbase + (size_t)kt * 64;
#pragma unroll
    for (int i = 0; i < 4; ++i) kreg[i] = *(const short8*)(kp + koff[i]);
#pragma unroll
    for (int i = 0; i < 4; ++i) vreg[i] = *(const short8*)(vp + voff[i]);
  };

  loadKV(0);

  for (int kt = 0; kt < 32; ++kt) {
    if (kt) {  // all waves done reading previous tile
      asm volatile("s_waitcnt lgkmcnt(0)" ::: "memory");
      __builtin_amdgcn_s_barrier();
      __builtin_amdgcn_sched_barrier(0);
    }
#pragma unroll
    for (int i = 0; i < 4; ++i) *(short8*)&Ksf[kldsoff[i]] = kreg[i];
#pragma unroll
    for (int i = 0; i < 4; ++i) *(short8*)&Vtl[vldsoff[i]] = vreg[i];
    if (kt + 1 < 32) loadKV(kt + 1);  // overlap next-tile HBM latency with compute
    asm volatile("s_waitcnt lgkmcnt(0)" ::: "memory");
    __builtin_amdgcn_s_barrier();
    __builtin_amdgcn_sched_barrier(0);

    // S^T = K @ Q^T : A = K rows (kv), B = Q cols (q). st[kvblk] covers 32 kv x 32 q.
    floatx16 st[2];
    st[0] = (floatx16)(0.0f);
    st[1] = (floatx16)(0.0f);
    __builtin_amdgcn_s_setprio(1);
#pragma unroll
    for (int ks = 0; ks < 8; ++ks) {
      const short8 kf0 = *(const short8*)&Ksf[l31 * 136 + ks * 16 + hi * 8];
      const short8 kf1 = *(const short8*)&Ksf[(32 + l31) * 136 + ks * 16 + hi * 8];
      st[0] = MFMA32(kf0, qf2[ks], st[0]);
      st[1] = MFMA32(kf1, qf2[ks], st[1]);
    }
    __builtin_amdgcn_s_setprio(0);

    // static-max softmax + pack to bf16 pairs: pk[kvblk][a][i] holds P^T rows
    // (8a + 4*hi + 2i, +2i+1) of kv-block, col q = l31.
    int pk[2][4][2];
#pragma unroll
    for (int kvblk = 0; kvblk < 2; ++kvblk)
#pragma unroll
      for (int a = 0; a < 4; ++a)
#pragma unroll
        for (int i = 0; i < 2; ++i) {
          const float e0 = exp2f(fmaf(st[kvblk][4 * a + 2 * i], SC2, -OFF2));
          const float e1 = exp2f(fmaf(st[kvblk][4 * a + 2 * i + 1], SC2, -OFF2));
          asm("v_cvt_pk_bf16_f32 %0, %1, %2" : "=v"(pk[kvblk][a][i]) : "v"(e0), "v"(e1));
        }

    // O^T += V^T @ P^T ; l += 1 @ P^T.  B-frag assembly: lane needs kv rows
    // ks2*16 + hi*8 + 0..7; own half + partner half from lane^32.
#pragma unroll
    for (int kvblk = 0; kvblk < 2; ++kvblk) {
#pragma unroll
      for (int ks2 = 0; ks2 < 2; ++ks2) {
        const int x0 = pk[kvblk][2 * ks2][0], x1 = pk[kvblk][2 * ks2][1];
        const int y0 = pk[kvblk][2 * ks2 + 1][0], y1 = pk[kvblk][2 * ks2 + 1][1];
        const int sx0 = __shfl_xor(x0, 32), sx1 = __shfl_xor(x1, 32);
        const int sy0 = __shfl_xor(y0, 32), sy1 = __shfl_xor(y1, 32);
        union { int i[4]; short8 s; } u;
        u.i[0] = hi ? sy0 : x0;
        u.i[1] = hi ? sy1 : x1;
        u.i[2] = hi ? y0 : sx0;
        u.i[3] = hi ? y1 : sx1;
        const short8 pB = u.s;
        __builtin_amdgcn_s_setprio(1);
        lacc = MFMA32(ones, pB, lacc);
#pragma unroll
        for (int dblk = 0; dblk < 4; ++dblk) {
          const short8 vf =
              *(const short8*)&Vtl[(dblk * 32 + l31) * 72 + kvblk * 32 + ks2 * 16 + hi * 8];
          oacc[dblk] = MFMA32(vf, pB, oacc[dblk]);
        }
        __builtin_amdgcn_s_setprio(0);
      }
    }
  }

  // epilogue: normalize, transpose via LDS (per-wave region), coalesced store
  asm volatile("s_waitcnt lgkmcnt(0)" ::: "memory");
  __builtin_amdgcn_s_barrier();  // all waves done with K/V LDS before reuse

  const float inv = 1.0f / lacc[0];
  short* tw = SMEM + wid * 4352;  // [32 q][136 d-padded]
#pragma unroll
  for (int dblk = 0; dblk < 4; ++dblk)
#pragma unroll
    for (int a = 0; a < 4; ++a) {
      __hip_bfloat16 o4[4];
#pragma unroll
      for (int r = 0; r < 4; ++r) o4[r] = __float2bfloat16(oacc[dblk][4 * a + r] * inv);
      *(short4*)&tw[l31 * 136 + dblk * 32 + a * 8 + hi * 4] = *(const short4*)o4;
    }
  // per-wave region: in-wave LDS dependency, no extra barrier needed
  __hip_bfloat16* orow =
      Og + ((size_t)(b * 2048 + q0w + (lane >> 1))) * 2048 + h * 128 + (lane & 1) * 64;
  const short* trow = &tw[(lane >> 1) * 136 + (lane & 1) * 64];
#pragma unroll
  for (int c = 0; c < 8; ++c) {
    *(short8*)(orow + c * 8) = *(const short8*)(trow + c * 8);
  }
}

// ---------------- launch ----------------
extern "C" void kernel_launch(void* const* d_in, const int* in_sizes, int n_in,
                              void* d_out, int out_size, void* d_ws, size_t ws_size,
                              hipStream_t stream) {
  const float* hidden = (const float*)d_in[0];
  const float* cosb = (const float*)d_in[1];
  const float* sinb = (const float*)d_in[2];
  const float* Wq = (const float*)d_in[3];
  const float* Wk = (const float*)d_in[4];
  const float* Wv = (const float*)d_in[5];
  const float* Wo = (const float*)d_in[6];
  const float* qw = (const float*)d_in[7];
  const float* kw = (const float*)d_in[8];

  char* ws = (char*)d_ws;
  __hip_bfloat16* hidden_bf = (__hip_bfloat16*)ws; ws += (size_t)4096 * 2048 * 2;
  __hip_bfloat16* wqkv = (__hip_bfloat16*)ws;      ws += (size_t)3072 * 2048 * 2;
  __hip_bfloat16* wo_bf = (__hip_bfloat16*)ws;     ws += (size_t)2048 * 2048 * 2;
  __hip_bfloat16* qkv = (__hip_bfloat16*)ws;       ws += (size_t)4096 * 3072 * 2;
  __hip_bfloat16* Qb = (__hip_bfloat16*)ws;        ws += (size_t)2 * 16 * 2048 * 128 * 2;
  __hip_bfloat16* Kb = (__hip_bfloat16*)ws;        ws += (size_t)2 * 4 * 2048 * 128 * 2;
  __hip_bfloat16* Vb = (__hip_bfloat16*)ws;        ws += (size_t)2 * 4 * 2048 * 128 * 2;
  __hip_bfloat16* attn = (__hip_bfloat16*)ws;      ws += (size_t)4096 * 2048 * 2;
  // Vt aliases wqkv (dead after gemm1; rewritten by f2bf every call -> deterministic)
  __hip_bfloat16* Vt = wqkv;

  f2bf<<<1024, 256, 0, stream>>>(hidden, hidden_bf, 4096 * 2048);
  f2bf<<<1024, 256, 0, stream>>>(Wq, wqkv, 2048 * 2048);
  f2bf<<<512, 256, 0, stream>>>(Wk, wqkv + (size_t)2048 * 2048, 512 * 2048);
  f2bf<<<512, 256, 0, stream>>>(Wv, wqkv + (size_t)2560 * 2048, 512 * 2048);
  f2bf<<<1024, 256, 0, stream>>>(Wo, wo_bf, 2048 * 2048);

  gemm_bt<__hip_bfloat16><<<dim3(32, 24), 256, 0, stream>>>(hidden_bf, wqkv, qkv, 4096, 3072, 2048);
  normrope<<<4096, 256, 0, stream>>>(qkv, cosb, sinb, qw, kw, Qb, Kb, Vb);
  vtrans<<<dim3(32, 2, 8), 256, 0, stream>>>(Vb, Vt);
  fattn<<<dim3(16, 32), 256, 0, stream>>>(Qb, Kb, Vt, attn);
  gemm_bt<float><<<dim3(32, 16), 256, 0, stream>>>(attn, wo_bf, (float*)d_out, 4096, 2048, 2048);
}

// Round 6
// 243.512 us; speedup vs baseline: 1.0297x; 1.0297x over previous
//
#include <hip/hip_runtime.h>
#include <hip/hip_bf16.h>
#include <stdint.h>

typedef __attribute__((ext_vector_type(8))) short short8;
typedef __attribute__((ext_vector_type(4))) float floatx4;
typedef __attribute__((ext_vector_type(16))) float floatx16;

#define MFMA16(a, b, c) __builtin_amdgcn_mfma_f32_16x16x32_bf16(a, b, c, 0, 0, 0)
#define MFMA32(a, b, c) __builtin_amdgcn_mfma_f32_32x32x16_bf16(a, b, c, 0, 0, 0)

static __device__ __forceinline__ void gload_lds16(const __hip_bfloat16* g, __hip_bfloat16* l) {
  __builtin_amdgcn_global_load_lds(
      (const __attribute__((address_space(1))) void*)g,
      (__attribute__((address_space(3))) void*)l,
      16, 0, 0);
}

// ---------------- fp32 -> bf16 convert ----------------
__global__ void f2bf(const float* __restrict__ in, __hip_bfloat16* __restrict__ out, int n) {
  const int stride = gridDim.x * blockDim.x * 4;
  for (int i = (blockIdx.x * blockDim.x + threadIdx.x) * 4; i < n; i += stride) {
    const float4 v = *(const float4*)(in + i);
    __hip_bfloat16 t[4] = {__float2bfloat16(v.x), __float2bfloat16(v.y),
                           __float2bfloat16(v.z), __float2bfloat16(v.w)};
    *(short4*)(out + i) = *(const short4*)t;
  }
}

// ---------------- GEMM: C = A @ Bt^T  (A: MxK, Bt: NxK, both bf16 row-major) ----------------
template <typename OUT_T>
__global__ __launch_bounds__(256)
void gemm_bt(const __hip_bfloat16* __restrict__ A, const __hip_bfloat16* __restrict__ Bt,
             OUT_T* __restrict__ C, int M, int N, int K) {
  __shared__ __hip_bfloat16 As[2][128 * 32];
  __shared__ __hip_bfloat16 Bs[2][128 * 32];
  const int tid = threadIdx.x;
  const int wid = tid >> 6, lane = tid & 63;
  const int lg = lane >> 4, lr = lane & 15;
  const int wr = wid >> 1, wc = wid & 1;
  const int m0 = blockIdx.x * 128, n0 = blockIdx.y * 128;
  const int nk = K >> 5;

  floatx4 acc[4][4];
#pragma unroll
  for (int mi = 0; mi < 4; ++mi)
#pragma unroll
    for (int ni = 0; ni < 4; ++ni) acc[mi][ni] = (floatx4)(0.0f);

  auto stage = [&](int buf, int kt) {
    const int k0 = kt << 5;
#pragma unroll
    for (int i = 0; i < 2; ++i) {
      const int e = (i * 256 + tid) * 8;
      const int row = e >> 5, col = e & 31;
      gload_lds16(A + (size_t)(m0 + row) * K + k0 + col, &As[buf][e]);
    }
#pragma unroll
    for (int i = 0; i < 2; ++i) {
      const int e = (i * 256 + tid) * 8;
      const int row = e >> 5, col = e & 31;
      gload_lds16(Bt + (size_t)(n0 + row) * K + k0 + col, &Bs[buf][e]);
    }
  };

  stage(0, 0);
  __syncthreads();

  for (int kt = 0; kt < nk; ++kt) {
    const int cur = kt & 1;
    if (kt + 1 < nk) stage(cur ^ 1, kt + 1);
    short8 af[4], bfr[4];
#pragma unroll
    for (int mi = 0; mi < 4; ++mi)
      af[mi] = *(const short8*)&As[cur][(wr * 64 + mi * 16 + lr) * 32 + lg * 8];
#pragma unroll
    for (int ni = 0; ni < 4; ++ni)
      bfr[ni] = *(const short8*)&Bs[cur][(wc * 64 + ni * 16 + lr) * 32 + lg * 8];
#pragma unroll
    for (int mi = 0; mi < 4; ++mi)
#pragma unroll
      for (int ni = 0; ni < 4; ++ni) acc[mi][ni] = MFMA16(af[mi], bfr[ni], acc[mi][ni]);
    __syncthreads();
  }

#pragma unroll
  for (int mi = 0; mi < 4; ++mi)
#pragma unroll
    for (int ni = 0; ni < 4; ++ni) {
      const int row = m0 + wr * 64 + mi * 16 + lg * 4;
      const int col = n0 + wc * 64 + ni * 16 + lr;
#pragma unroll
      for (int r = 0; r < 4; ++r) {
        C[(size_t)(row + r) * N + col] = (OUT_T)acc[mi][ni][r];
      }
    }
}

// ---------------- RMSNorm + RoPE + scatter to (B,H,S,D) ----------------
__global__ __launch_bounds__(256)
void normrope(const __hip_bfloat16* __restrict__ qkv, const float* __restrict__ cosb,
              const float* __restrict__ sinb, const float* __restrict__ qw,
              const float* __restrict__ kw, __hip_bfloat16* __restrict__ Q,
              __hip_bfloat16* __restrict__ K, __hip_bfloat16* __restrict__ V) {
  const int m = blockIdx.x;            // b*2048 + s
  const int b = m >> 11, s = m & 2047;
  const int wid = threadIdx.x >> 6, lane = threadIdx.x & 63;
  const size_t qkvrow = (size_t)m * 3072;
  const float c1 = cosb[(size_t)m * 128 + lane], s1 = sinb[(size_t)m * 128 + lane];
  const float c2 = cosb[(size_t)m * 128 + lane + 64], s2 = sinb[(size_t)m * 128 + lane + 64];
  for (int h = wid * 6; h < wid * 6 + 6; ++h) {
    const float x1 = __bfloat162float(qkv[qkvrow + h * 128 + lane]);
    const float x2 = __bfloat162float(qkv[qkvrow + h * 128 + lane + 64]);
    if (h < 20) {
      float ss = x1 * x1 + x2 * x2;
      ss += __shfl_xor(ss, 1);  ss += __shfl_xor(ss, 2);  ss += __shfl_xor(ss, 4);
      ss += __shfl_xor(ss, 8);  ss += __shfl_xor(ss, 16); ss += __shfl_xor(ss, 32);
      const float rs = rsqrtf(ss * (1.0f / 128.0f) + 1e-6f);
      const float* w = (h < 16) ? qw : kw;
      const float n1 = x1 * rs * w[lane], n2 = x2 * rs * w[lane + 64];
      const float o1 = n1 * c1 - n2 * s1;
      const float o2 = n2 * c2 + n1 * s2;
      if (h < 16) {
        const size_t base = ((size_t)(b * 16 + h) * 2048 + s) * 128;
        Q[base + lane] = __float2bfloat16(o1);
        Q[base + lane + 64] = __float2bfloat16(o2);
      } else {
        const size_t base = ((size_t)(b * 4 + h - 16) * 2048 + s) * 128;
        K[base + lane] = __float2bfloat16(o1);
        K[base + lane + 64] = __float2bfloat16(o2);
      }
    } else {
      const size_t base = ((size_t)(b * 4 + h - 20) * 2048 + s) * 128;
      V[base + lane] = qkv[qkvrow + h * 128 + lane];
      V[base + lane + 64] = qkv[qkvrow + h * 128 + lane + 64];
    }
  }
}

// ---------------- V transpose: (BHkv,S,D) -> (BHkv,D,S_perm) ----------------
// Column order permuted within each 32-block so PV B-frags are lane-local:
// pos p -> physical kv (p&3) + ((p>>2)&1)*8 + ((p>>3)&1)*4 + (p&16)   (involution)
__global__ __launch_bounds__(256)
void vtrans(const __hip_bfloat16* __restrict__ V, __hip_bfloat16* __restrict__ Vt) {
  __shared__ short L[64 * 65];  // [d_local][s_local], stride 65 kills bank conflicts
  const int tid = threadIdx.x;
  const int s0 = blockIdx.x * 64, d0 = blockIdx.y * 64, bz = blockIdx.z;
  const __hip_bfloat16* src = V + (size_t)bz * 2048 * 128;
#pragma unroll
  for (int i = 0; i < 2; ++i) {
    const int slot = i * 256 + tid;
    const int srow = slot >> 3, c8 = (slot & 7) * 8;
    short8 v = *(const short8*)(src + (size_t)(s0 + srow) * 128 + d0 + c8);
#pragma unroll
    for (int j = 0; j < 8; ++j) L[(c8 + j) * 65 + srow] = v[j];
  }
  __syncthreads();
  __hip_bfloat16* dst = Vt + (size_t)bz * 128 * 2048;
#pragma unroll
  for (int i = 0; i < 2; ++i) {
    const int slot = i * 256 + tid;
    const int drow = slot >> 3, sc8 = (slot & 7) * 8;
    short8 o;
#pragma unroll
    for (int j = 0; j < 8; ++j) {
      const int p = sc8 + j;
      const int pb = p & 31;
      const int phys = (p & ~31) | ((pb & 3) + ((pb >> 2) & 1) * 8 + ((pb >> 3) & 1) * 4 + (pb & 16));
      o[j] = L[drow * 65 + phys];
    }
    *(short8*)(dst + (size_t)(d0 + drow) * 2048 + s0 + sc8) = o;
  }
}

// ---------------- Flash attention (non-causal, GQA 4:1), 32x32 MFMA, S^T form ----------------
// Zero-shuffle PV: V^T columns pre-permuted so the PV B-fragment is the lane's own
// packed st registers. Static-max softmax, l via ones-MFMA, LDS double-buffered
// (one barrier per tile), reg prefetch of next tile.
__global__ __launch_bounds__(256, 2)
void fattn(const __hip_bfloat16* __restrict__ Qg, const __hip_bfloat16* __restrict__ Kg,
           const __hip_bfloat16* __restrict__ Vtg, __hip_bfloat16* __restrict__ Og) {
  __shared__ short SMEM[2][17920];  // per buf: Ksf [64][136] (8704) + Vtl [128][72] (9216)

  const int tid = threadIdx.x, wid = tid >> 6, lane = tid & 63;
  const int l31 = lane & 31, hi = lane >> 5;
  const int qt = blockIdx.x, bh = blockIdx.y;
  const int b = bh >> 4, h = bh & 15, hkv = h >> 2;
  const int q0w = qt * 128 + wid * 32;

  // Q as B-fragments for 32x32x16: B[col = l31 -> q][k = hi*8 + j], k-step 16 over d
  const __hip_bfloat16* Qrow = Qg + ((size_t)((b * 16 + h) * 2048 + q0w + l31)) * 128;
  short8 qf2[8];
#pragma unroll
  for (int ks = 0; ks < 8; ++ks) qf2[ks] = *(const short8*)(Qrow + ks * 16 + hi * 8);

  const __hip_bfloat16* Kbase = Kg + (size_t)(b * 4 + hkv) * 2048 * 128;
  const __hip_bfloat16* Vtbase = Vtg + (size_t)(b * 4 + hkv) * 128 * 2048;

  int koff[4], kldsoff[4], voff[4], vldsoff[4];
#pragma unroll
  for (int i = 0; i < 4; ++i) {
    const int idx = i * 256 + tid;
    const int kkv = idx >> 4, kd = (idx & 15) * 8;
    koff[i] = kkv * 128 + kd;
    kldsoff[i] = kkv * 136 + kd;
    const int vd = idx >> 3, vc = (idx & 7) * 8;
    voff[i] = vd * 2048 + vc;
    vldsoff[i] = 8704 + vd * 72 + vc;
  }

  // oacc[dblk]: O^T[d = dblk*32 + (reg&3)+8*(reg>>2)+4*hi][q = l31]
  floatx16 oacc[4];
#pragma unroll
  for (int dblk = 0; dblk < 4; ++dblk) oacc[dblk] = (floatx16)(0.0f);
  floatx16 lacc = (floatx16)(0.0f);

  short8 ones;
#pragma unroll
  for (int j = 0; j < 8; ++j) ones[j] = (short)0x3F80;  // bf16 1.0

  const float SC2 = 0.12753102497113446f;   // (1/sqrt(128)) * log2(e)
  const float OFF2 = 17.31234049066756f;    // 12 * log2(e)

  short8 kreg[4], vreg[4];
  auto loadKV = [&](int kt) {
    const __hip_bfloat16* kp = Kbase + (size_t)kt * 64 * 128;
    const __hip_bfloat16* vp = Vtbase + (size_t)kt * 64;
#pragma unroll
    for (int i = 0; i < 4; ++i) kreg[i] = *(const short8*)(kp + koff[i]);
#pragma unroll
    for (int i = 0; i < 4; ++i) vreg[i] = *(const short8*)(vp + voff[i]);
  };

  // prologue: tile 0 into buf0, prefetch tile 1 into regs
  loadKV(0);
#pragma unroll
  for (int i = 0; i < 4; ++i) *(short8*)&SMEM[0][kldsoff[i]] = kreg[i];
#pragma unroll
  for (int i = 0; i < 4; ++i) *(short8*)&SMEM[0][vldsoff[i]] = vreg[i];
  loadKV(1);
  asm volatile("s_waitcnt lgkmcnt(0)" ::: "memory");
  __builtin_amdgcn_s_barrier();
  __builtin_amdgcn_sched_barrier(0);

  for (int kt = 0; kt < 32; ++kt) {
    const int cur = kt & 1;
    const short* Ksf = SMEM[cur];
    const short* Vtl = SMEM[cur];  // V at +8704 inside buffer
    // stage tile kt+1 into the other buffer; prefetch tile kt+2 into regs
    if (kt + 1 < 32) {
      short* nb = SMEM[cur ^ 1];
#pragma unroll
      for (int i = 0; i < 4; ++i) *(short8*)&nb[kldsoff[i]] = kreg[i];
#pragma unroll
      for (int i = 0; i < 4; ++i) *(short8*)&nb[vldsoff[i]] = vreg[i];
      if (kt + 2 < 32) loadKV(kt + 2);
    }

    // S^T = K @ Q^T : A = K rows (kv), B = Q cols (q). st[kvblk] covers 32 kv x 32 q.
    floatx16 st[2];
    st[0] = (floatx16)(0.0f);
    st[1] = (floatx16)(0.0f);
    __builtin_amdgcn_s_setprio(1);
#pragma unroll
    for (int ks = 0; ks < 8; ++ks) {
      const short8 kf0 = *(const short8*)&Ksf[l31 * 136 + ks * 16 + hi * 8];
      const short8 kf1 = *(const short8*)&Ksf[(32 + l31) * 136 + ks * 16 + hi * 8];
      st[0] = MFMA32(kf0, qf2[ks], st[0]);
      st[1] = MFMA32(kf1, qf2[ks], st[1]);
    }
    __builtin_amdgcn_s_setprio(0);

    // static-max softmax + pack: pk[kvblk][m] = bf16x2 of (exp(st[2m]), exp(st[2m+1]))
    int pk[2][8];
#pragma unroll
    for (int kvblk = 0; kvblk < 2; ++kvblk)
#pragma unroll
      for (int m = 0; m < 8; ++m) {
        const float e0 = exp2f(fmaf(st[kvblk][2 * m], SC2, -OFF2));
        const float e1 = exp2f(fmaf(st[kvblk][2 * m + 1], SC2, -OFF2));
        asm("v_cvt_pk_bf16_f32 %0, %1, %2" : "=v"(pk[kvblk][m]) : "v"(e0), "v"(e1));
      }

    // O^T += V^T @ P^T ; l += 1 @ P^T. B-frag = lane's own packed regs (kv-perm
    // baked into V^T column order) — zero cross-lane traffic.
#pragma unroll
    for (int kvblk = 0; kvblk < 2; ++kvblk) {
#pragma unroll
      for (int s = 0; s < 2; ++s) {
        union { int i[4]; short8 s8; } u;
        u.i[0] = pk[kvblk][4 * s + 0];
        u.i[1] = pk[kvblk][4 * s + 1];
        u.i[2] = pk[kvblk][4 * s + 2];
        u.i[3] = pk[kvblk][4 * s + 3];
        const short8 pB = u.s8;
        __builtin_amdgcn_s_setprio(1);
        lacc = MFMA32(ones, pB, lacc);
#pragma unroll
        for (int dblk = 0; dblk < 4; ++dblk) {
          const short8 vf =
              *(const short8*)&Vtl[8704 + (dblk * 32 + l31) * 72 + kvblk * 32 + s * 16 + hi * 8];
          oacc[dblk] = MFMA32(vf, pB, oacc[dblk]);
        }
        __builtin_amdgcn_s_setprio(0);
      }
    }

    asm volatile("s_waitcnt lgkmcnt(0)" ::: "memory");
    __builtin_amdgcn_s_barrier();
    __builtin_amdgcn_sched_barrier(0);
  }

  // epilogue: normalize, transpose via per-wave LDS region, coalesced store
  const float inv = 1.0f / lacc[0];
  short* tw = &SMEM[0][0] + wid * 4352;  // [32 q][136 d-padded]
#pragma unroll
  for (int dblk = 0; dblk < 4; ++dblk)
#pragma unroll
    for (int a = 0; a < 4; ++a) {
      __hip_bfloat16 o4[4];
#pragma unroll
      for (int r = 0; r < 4; ++r) o4[r] = __float2bfloat16(oacc[dblk][4 * a + r] * inv);
      *(short4*)&tw[l31 * 136 + dblk * 32 + a * 8 + hi * 4] = *(const short4*)o4;
    }
  __hip_bfloat16* orow =
      Og + ((size_t)(b * 2048 + q0w + (lane >> 1))) * 2048 + h * 128 + (lane & 1) * 64;
  const short* trow = &tw[(lane >> 1) * 136 + (lane & 1) * 64];
#pragma unroll
  for (int c = 0; c < 8; ++c) {
    *(short8*)(orow + c * 8) = *(const short8*)(trow + c * 8);
  }
}

// ---------------- launch ----------------
extern "C" void kernel_launch(void* const* d_in, const int* in_sizes, int n_in,
                              void* d_out, int out_size, void* d_ws, size_t ws_size,
                              hipStream_t stream) {
  const float* hidden = (const float*)d_in[0];
  const float* cosb = (const float*)d_in[1];
  const float* sinb = (const float*)d_in[2];
  const float* Wq = (const float*)d_in[3];
  const float* Wk = (const float*)d_in[4];
  const float* Wv = (const float*)d_in[5];
  const float* Wo = (const float*)d_in[6];
  const float* qw = (const float*)d_in[7];
  const float* kw = (const float*)d_in[8];

  char* ws = (char*)d_ws;
  __hip_bfloat16* hidden_bf = (__hip_bfloat16*)ws; ws += (size_t)4096 * 2048 * 2;
  __hip_bfloat16* wqkv = (__hip_bfloat16*)ws;      ws += (size_t)3072 * 2048 * 2;
  __hip_bfloat16* wo_bf = (__hip_bfloat16*)ws;     ws += (size_t)2048 * 2048 * 2;
  __hip_bfloat16* qkv = (__hip_bfloat16*)ws;       ws += (size_t)4096 * 3072 * 2;
  __hip_bfloat16* Qb = (__hip_bfloat16*)ws;        ws += (size_t)2 * 16 * 2048 * 128 * 2;
  __hip_bfloat16* Kb = (__hip_bfloat16*)ws;        ws += (size_t)2 * 4 * 2048 * 128 * 2;
  __hip_bfloat16* Vb = (__hip_bfloat16*)ws;        ws += (size_t)2 * 4 * 2048 * 128 * 2;
  __hip_bfloat16* attn = (__hip_bfloat16*)ws;      ws += (size_t)4096 * 2048 * 2;
  // Vt aliases wqkv (dead after gemm1; rewritten by f2bf every call -> deterministic)
  __hip_bfloat16* Vt = wqkv;

  f2bf<<<1024, 256, 0, stream>>>(hidden, hidden_bf, 4096 * 2048);
  f2bf<<<1024, 256, 0, stream>>>(Wq, wqkv, 2048 * 2048);
  f2bf<<<512, 256, 0, stream>>>(Wk, wqkv + (size_t)2048 * 2048, 512 * 2048);
  f2bf<<<512, 256, 0, stream>>>(Wv, wqkv + (size_t)2560 * 2048, 512 * 2048);
  f2bf<<<1024, 256, 0, stream>>>(Wo, wo_bf, 2048 * 2048);

  gemm_bt<__hip_bfloat16><<<dim3(32, 24), 256, 0, stream>>>(hidden_bf, wqkv, qkv, 4096, 3072, 2048);
  normrope<<<4096, 256, 0, stream>>>(qkv, cosb, sinb, qw, kw, Qb, Kb, Vb);
  vtrans<<<dim3(32, 2, 8), 256, 0, stream>>>(Vb, Vt);
  fattn<<<dim3(16, 32), 256, 0, stream>>>(Qb, Kb, Vt, attn);
  gemm_bt<float><<<dim3(32, 16), 256, 0, stream>>>(attn, wo_bf, (float*)d_out, 4096, 2048, 2048);
}